// Round 11
// baseline (152.144 us; speedup 1.0000x reference)
//
#include <hip/hip_runtime.h>
#include <stdint.h>

#define BATCH 32
#define CH    256
#define TLEN  4096
#define TN    32            // timesteps per tile
#define NT    8             // tiles per block (block covers 256 t)
#define RNG   64            // sA ring rows (power of 2 -> free mod)
#define SST   36            // phase-B f32 scratch row stride

typedef short    bf16x8 __attribute__((ext_vector_type(8)));
typedef float    f32x4  __attribute__((ext_vector_type(4)));
typedef uint16_t u16x4  __attribute__((ext_vector_type(4)));

__device__ __attribute__((aligned(16))) uint16_t g_w1eff[CH * CH];
__device__ __attribute__((aligned(16))) float g_tap[5 * CH];   // tap-major
__device__ __attribute__((aligned(16))) float g_bias[CH];

static __device__ __forceinline__ uint16_t f32_to_bf16(float f) {
    uint32_t u = __builtin_bit_cast(uint32_t, f);
    u += 0x7FFFu + ((u >> 16) & 1u);
    return (uint16_t)(u >> 16);
}
static __device__ __forceinline__ float bf16_to_f32(uint16_t h) {
    uint32_t u = ((uint32_t)h) << 16;
    return __builtin_bit_cast(float, u);
}
// ring-row XOR swizzle: 8 distinct values across rows stepping by 4 (conflict-free
// scalar staging writes) while keeping col 8-u16 alignment for b128/u16x4 reads.
static __device__ __forceinline__ int swzr(int row) {
    return ((row ^ (row >> 2)) & 7) << 3;
}
// tanh-form gelu folded into exp2: gelu ~= x - x / (1 + 2^(x*(A + B*x^2)))
static __device__ __forceinline__ float gelu_fast(float x) {
    const float A = 2.3022082f;
    const float B = 0.10294331f;
    float x2 = x * x;
    float z  = x * fmaf(x2, B, A);
    float e  = exp2f(z);
    float r  = __builtin_amdgcn_rcpf(1.0f + e);
    return fmaf(-x, r, x);
}

__global__ void prep_kernel(const float* __restrict__ w1, const float* __restrict__ b1,
                            const float* __restrict__ w3, const float* __restrict__ b3,
                            const float* __restrict__ w5, const float* __restrict__ b5,
                            const float* __restrict__ wc, const float* __restrict__ bc) {
    const int o = blockIdx.x;
    const int c = threadIdx.x;
    const float wc0 = wc[o * 3 + 0];
    g_w1eff[o * CH + c] = f32_to_bf16(wc0 * w1[o * CH + c]);
    if (c == 0) {
        const float wc1 = wc[o * 3 + 1], wc2 = wc[o * 3 + 2];
        g_tap[0 * CH + o] = wc2 * w5[o * 5 + 0];
        g_tap[1 * CH + o] = wc1 * w3[o * 3 + 0] + wc2 * w5[o * 5 + 1];
        g_tap[2 * CH + o] = wc1 * w3[o * 3 + 1] + wc2 * w5[o * 5 + 2];
        g_tap[3 * CH + o] = wc1 * w3[o * 3 + 2] + wc2 * w5[o * 5 + 3];
        g_tap[4 * CH + o] = wc2 * w5[o * 5 + 4];
        g_bias[o] = wc0 * b1[o] + wc1 * b3[o] + wc2 * b5[o] + bc[o];
    }
}

// Persistent t-march: block = (batch b, 256-t strip), 8 tiles of 32 t.
// sA ring: row rho(tau) = (tau - t0b + 2) & 63 holds bf16(gelu(x[c][tau])),
// col c ^ swzr(row). Each tile stages its 32 NEW t from regs prefetched during
// the previous tile's compute; halos persist in the ring. Residual re-read from
// global (L2-hot). Two barriers per tile.
__global__ __launch_bounds__(256, 2)
void fused_kernel(const float* __restrict__ x, float* __restrict__ out) {
    __shared__ __attribute__((aligned(16))) uint16_t sA[RNG * CH];      // 32768 B
    __shared__ __attribute__((aligned(16))) float    sS[4 * 16 * SST];  //  9216 B

    const int tid  = threadIdx.x;
    const int lane = tid & 63;
    const int wid  = tid >> 6;
    const int b    = blockIdx.y;
    const int t0b  = blockIdx.x * (TN * NT);

    const float* __restrict__ xb = x + (size_t)b * CH * TLEN;
    float* __restrict__ ob = out + (size_t)b * CH * TLEN;

    // ---- prologue edge: rows 0..3  <-> tau = t0b-2 .. t0b+1, c = tid ----
    {
        const int c = tid;
        float v[4];
        if (blockIdx.x == 0) {
#pragma unroll
            for (int j = 0; j < 4; ++j) {
                const int gt = t0b - 2 + j;
                v[j] = (gt >= 0) ? xb[(size_t)c * TLEN + gt] : 0.0f;
            }
        } else {
            f32x4 vv = *(const f32x4*)(xb + (size_t)c * TLEN + (t0b - 2));
            v[0] = vv[0]; v[1] = vv[1]; v[2] = vv[2]; v[3] = vv[3];
        }
#pragma unroll
        for (int j = 0; j < 4; ++j)
            sA[j * CH + (c ^ swzr(j))] = f32_to_bf16(gelu_fast(v[j]));
    }

    const int cs = lane >> 3;       // channel-sub within wave
    const int q  = lane & 7;        // t-quad
    const int c0 = wid * 64;

    // ---- prologue prefetch: tau in [t0b+2, t0b+34) ----
    f32x4 vreg[8];
    {
        const int ts = t0b + 2 + q * 4;
#pragma unroll
        for (int r = 0; r < 8; ++r) {
            const int c = c0 + r * 8 + cs;
            vreg[r] = *(const f32x4*)(xb + (size_t)c * TLEN + ts);
        }
    }

    const int colt = lane & 15;
    const int rg   = (lane >> 4) * 4;
    const int kgrp = (lane >> 4) * 8;
    const int m0   = wid * 64;
    const int ci   = lane >> 2;
    const int qq   = lane & 3;
    float* __restrict__ sw = sS + wid * (16 * SST);

    for (int i = 0; i < NT; ++i) {
        // ---- STAGE: write gelu(vreg) into ring rows (32i+4 .. 32i+35)&63 ----
        {
            const int rb4 = (32 * i + 4) & 63;
#pragma unroll
            for (int r = 0; r < 8; ++r) {
                const int c = c0 + r * 8 + cs;
#pragma unroll
                for (int j = 0; j < 4; ++j) {
                    const int row = (rb4 + q * 4 + j) & 63;
                    sA[row * CH + (c ^ swzr(row))] = f32_to_bf16(gelu_fast(vreg[r][j]));
                }
            }
        }
        __syncthreads();   // B1: tile data visible to all waves

        // ---- PREFETCH tile i+1 (overlaps K-loop + epilogue) ----
        if (i + 1 < NT) {
            const int ts = t0b + 32 * (i + 1) + 2 + q * 4;
            if (ts + 4 <= TLEN) {
#pragma unroll
                for (int r = 0; r < 8; ++r) {
                    const int c = c0 + r * 8 + cs;
                    vreg[r] = *(const f32x4*)(xb + (size_t)c * TLEN + ts);
                }
            } else {  // only the global tail strip
#pragma unroll
                for (int r = 0; r < 8; ++r) {
                    const int c = c0 + r * 8 + cs;
#pragma unroll
                    for (int j = 0; j < 4; ++j)
                        vreg[r][j] = (ts + j < TLEN) ? xb[(size_t)c * TLEN + ts + j] : 0.0f;
                }
            }
        }

        // ---- K-loop (1-deep ping-pong), B-frag ring rows fixed per tile ----
        int rowB[2], swzB[2];
#pragma unroll
        for (int ni = 0; ni < 2; ++ni) {
            const int row = (32 * i + 2 + ni * 16 + colt) & 63;
            rowB[ni] = row * CH;
            swzB[ni] = swzr(row);
        }

        f32x4 acc[4][2];
        const f32x4 vzero = {0.f, 0.f, 0.f, 0.f};
#pragma unroll
        for (int mi = 0; mi < 4; ++mi)
#pragma unroll
            for (int ni = 0; ni < 2; ++ni) acc[mi][ni] = vzero;

        bf16x8 afb[2][4], bfb[2][2];
#pragma unroll
        for (int mi = 0; mi < 4; ++mi) {
            const int co = m0 + mi * 16 + colt;
            afb[0][mi] = *(const bf16x8*)(g_w1eff + co * CH + kgrp);
        }
#pragma unroll
        for (int ni = 0; ni < 2; ++ni)
            bfb[0][ni] = *(const bf16x8*)(&sA[rowB[ni] + (kgrp ^ swzB[ni])]);
#pragma unroll
        for (int s = 0; s < 8; ++s) {
            const int cur = s & 1, nxt = cur ^ 1;
            if (s < 7) {
                const int kk = (s + 1) * 32;
#pragma unroll
                for (int mi = 0; mi < 4; ++mi) {
                    const int co = m0 + mi * 16 + colt;
                    afb[nxt][mi] = *(const bf16x8*)(g_w1eff + co * CH + kk + kgrp);
                }
                const int cin = kk + kgrp;
#pragma unroll
                for (int ni = 0; ni < 2; ++ni)
                    bfb[nxt][ni] = *(const bf16x8*)(&sA[rowB[ni] + (cin ^ swzB[ni])]);
            }
#pragma unroll
            for (int mi = 0; mi < 4; ++mi)
#pragma unroll
                for (int ni = 0; ni < 2; ++ni)
                    acc[mi][ni] = __builtin_amdgcn_mfma_f32_16x16x32_bf16(afb[cur][mi], bfb[cur][ni], acc[mi][ni], 0, 0, 0);
        }

        // ---- PHASE A: depthwise + bias folded into acc ----
        int rowA[2][5], swzA[2][5];
#pragma unroll
        for (int ni = 0; ni < 2; ++ni)
#pragma unroll
            for (int k = 0; k < 5; ++k) {
                const int row = (32 * i + ni * 16 + colt + k) & 63;
                rowA[ni][k] = row * CH;
                swzA[ni][k] = swzr(row);
            }
#pragma unroll
        for (int mi = 0; mi < 4; ++mi) {
            const int c = m0 + mi * 16 + rg;
            const f32x4 tp0 = *(const f32x4*)(g_tap + 0 * CH + c);
            const f32x4 tp1 = *(const f32x4*)(g_tap + 1 * CH + c);
            const f32x4 tp2 = *(const f32x4*)(g_tap + 2 * CH + c);
            const f32x4 tp3 = *(const f32x4*)(g_tap + 3 * CH + c);
            const f32x4 tp4 = *(const f32x4*)(g_tap + 4 * CH + c);
            const f32x4 bsv = *(const f32x4*)(g_bias + c);
#pragma unroll
            for (int ni = 0; ni < 2; ++ni) {
                u16x4 a0 = *(const u16x4*)(&sA[rowA[ni][0] + (c ^ swzA[ni][0])]);
                u16x4 a1 = *(const u16x4*)(&sA[rowA[ni][1] + (c ^ swzA[ni][1])]);
                u16x4 a2 = *(const u16x4*)(&sA[rowA[ni][2] + (c ^ swzA[ni][2])]);
                u16x4 a3 = *(const u16x4*)(&sA[rowA[ni][3] + (c ^ swzA[ni][3])]);
                u16x4 a4 = *(const u16x4*)(&sA[rowA[ni][4] + (c ^ swzA[ni][4])]);
#pragma unroll
                for (int r = 0; r < 4; ++r) {
                    float d = tp0[r] * bf16_to_f32(a0[r]);
                    d = fmaf(tp1[r], bf16_to_f32(a1[r]), d);
                    d = fmaf(tp2[r], bf16_to_f32(a2[r]), d);
                    d = fmaf(tp3[r], bf16_to_f32(a3[r]), d);
                    d = fmaf(tp4[r], bf16_to_f32(a4[r]), d);
                    acc[mi][ni][r] += d + bsv[r];
                }
            }
        }
        __syncthreads();   // B2: sA reads of tile i done; next STAGE may overwrite

        // ---- PHASE B: residual loads first (L2-hot), then wave-private transpose ----
        const int tg0 = t0b + 32 * i;
        f32x4 xv[4][2];
#pragma unroll
        for (int mi = 0; mi < 4; ++mi) {
            const int cc = m0 + mi * 16 + ci;
            const float* xrow = xb + (size_t)cc * TLEN + tg0 + qq * 8;
            xv[mi][0] = *(const f32x4*)(xrow + 0);
            xv[mi][1] = *(const f32x4*)(xrow + 4);
        }
#pragma unroll
        for (int mi = 0; mi < 4; ++mi) {
#pragma unroll
            for (int ni = 0; ni < 2; ++ni) {
                const int t = ni * 16 + colt;
#pragma unroll
                for (int r = 0; r < 4; ++r) sw[(rg + r) * SST + t] = acc[mi][ni][r];
            }
            const int cc = m0 + mi * 16 + ci;
            float* orow = ob + (size_t)cc * TLEN + tg0 + qq * 8;
            const float* srow = sw + ci * SST + qq * 8;
            f32x4 s0 = *(const f32x4*)(srow + 0);
            f32x4 s1 = *(const f32x4*)(srow + 4);
            *(f32x4*)(orow + 0) = s0 + xv[mi][0];
            *(f32x4*)(orow + 4) = s1 + xv[mi][1];
        }
    }
}

extern "C" void kernel_launch(void* const* d_in, const int* in_sizes, int n_in,
                              void* d_out, int out_size, void* d_ws, size_t ws_size,
                              hipStream_t stream) {
    const float* x  = (const float*)d_in[0];
    const float* w1 = (const float*)d_in[1];
    const float* b1 = (const float*)d_in[2];
    const float* w3 = (const float*)d_in[3];
    const float* b3 = (const float*)d_in[4];
    const float* w5 = (const float*)d_in[5];
    const float* b5 = (const float*)d_in[6];
    const float* wc = (const float*)d_in[7];
    const float* bc = (const float*)d_in[8];
    float* out = (float*)d_out;

    prep_kernel<<<dim3(CH), dim3(CH), 0, stream>>>(w1, b1, w3, b3, w5, b5, wc, bc);
    fused_kernel<<<dim3(TLEN / (TN * NT), BATCH), dim3(256), 0, stream>>>(x, out);
}